// Round 1
// baseline (223.071 us; speedup 1.0000x reference)
//
#include <hip/hip_runtime.h>
#include <hip/hip_bf16.h>

// Problem constants (from reference): C=32, H=64, CO=32. N, M, E derived from in_sizes.
#define C_IN 32
#define HDIM 64
#define C_OUT 32

__device__ __forceinline__ float bf16_to_f32(unsigned short u) {
    unsigned int x = ((unsigned int)u) << 16;
    return __uint_as_float(x);
}

__device__ __forceinline__ unsigned short f32_to_bf16(float f) {
    unsigned int x = __float_as_uint(f);
    unsigned int lsb = (x >> 16) & 1u;
    x += 0x7fffu + lsb;   // round-to-nearest-even
    return (unsigned short)(x >> 16);
}

// Exact-ish GELU: 0.5*x*(1+erf(x/sqrt(2))), erf via Abramowitz-Stegun 7.1.26 (|err|<1.5e-7)
__device__ __forceinline__ float gelu_f(float x) {
    float z  = x * 0.70710678118654752f;
    float az = fabsf(z);
    float t  = __builtin_amdgcn_rcpf(fmaf(0.3275911f, az, 1.0f));
    float poly = t * fmaf(t, fmaf(t, fmaf(t, fmaf(t, 1.061405429f, -1.453152027f),
                                          1.421413741f), -0.284496736f), 0.254829592f);
    float e = __expf(-z * z);
    float erf_az = fmaf(-poly, e, 1.0f);
    float erf_z  = copysignf(erf_az, z);
    return 0.5f * x * (1.0f + erf_z);
}

// Phase 1+2: U[n] = in_features[n] @ W1[:32]          (bf16, N rows)
//            S[m] = out_features[m] @ W1[32:] + b1    (bf16, M rows)
// One wave per row, lane = output channel (64 channels).
__global__ __launch_bounds__(256) void proj_kernel(
    const float* __restrict__ in_features, const float* __restrict__ out_features,
    const float* __restrict__ W1, const float* __restrict__ b1,
    unsigned short* __restrict__ U, unsigned short* __restrict__ S,
    int N, int M)
{
    int wid  = (blockIdx.x * blockDim.x + threadIdx.x) >> 6;
    int lane = threadIdx.x & 63;
    if (wid >= N + M) return;
    bool isS = wid >= N;
    const float* x  = isS ? (out_features + (size_t)(wid - N) * C_IN)
                          : (in_features  + (size_t)wid * C_IN);
    const float* w1 = W1 + (isS ? C_IN * HDIM : 0);
    float acc = isS ? b1[lane] : 0.0f;
#pragma unroll
    for (int k = 0; k < C_IN; ++k) {
        acc = fmaf(x[k], w1[k * HDIM + lane], acc);
    }
    unsigned short* dst = isS ? (S + (size_t)(wid - N) * HDIM)
                              : (U + (size_t)wid * HDIM);
    dst[lane] = f32_to_bf16(acc);
}

// Phase 3 (fused with phase 4): per segment m:
//   acc[k] = sum_e w_e * gelu(U[idx_e][k] + S[m][k])       (k = lane, 64 channels)
//   out[m][j] = (acc @ W2)[j]/cnt + b2[j]*wsum/cnt
// One wave per segment; 4 waves (4 segments) per 256-thread block.
__global__ __launch_bounds__(256) void conv_kernel(
    const unsigned short* __restrict__ U, const unsigned short* __restrict__ S,
    const int* __restrict__ nbr, const int* __restrict__ rowptr,
    const float* __restrict__ in_weights,
    const float* __restrict__ W2, const float* __restrict__ b2,
    float* __restrict__ out, int M)
{
    __shared__ float lds_W2[HDIM * C_OUT];   // 8 KB
    __shared__ float lds_acc[4 * HDIM];      // 1 KB

    int tid = threadIdx.x;
#pragma unroll
    for (int i = tid; i < HDIM * C_OUT; i += 256) lds_W2[i] = W2[i];

    int wave = tid >> 6, lane = tid & 63;
    int m = blockIdx.x * 4 + wave;

    float acc = 0.0f, wsum = 0.0f;
    int cnt = 0;
    if (m < M) {
        int base = rowptr[m];
        cnt = rowptr[m + 1] - base;
        float s = bf16_to_f32(S[(size_t)m * HDIM + lane]);

        for (int t0 = 0; t0 < cnt; t0 += 64) {
            int chunk = min(64, cnt - t0);
            int id = 0; float w = 0.0f;
            if (lane < chunk) {
                id = nbr[base + t0 + lane];
                w  = in_weights[id];
            }
#pragma unroll 4
            for (int t = 0; t < chunk; ++t) {
                int   idt = __shfl(id, t);
                float wt  = __shfl(w, t);
                const unsigned short* Urow = U + (size_t)((unsigned)idt) * HDIM;
                float u = bf16_to_f32(Urow[lane]);
                float g = gelu_f(u + s);
                acc  = fmaf(wt, g, acc);
                wsum += wt;
            }
        }
    }

    lds_acc[wave * HDIM + lane] = acc;
    __syncthreads();

    if (m < M) {
        int j = lane & 31, half = lane >> 5;
        float o = 0.0f;
#pragma unroll
        for (int k2 = 0; k2 < 32; ++k2) {
            int k = half * 32 + k2;
            o = fmaf(lds_acc[wave * HDIM + k], lds_W2[k * C_OUT + j], o);
        }
        o += __shfl_xor(o, 32);   // combine the two k-halves
        if (lane < 32) {
            float invc = 1.0f / (float)max(cnt, 1);
            out[(size_t)m * C_OUT + lane] = (o + b2[lane] * wsum) * invc;
        }
    }
}

extern "C" void kernel_launch(void* const* d_in, const int* in_sizes, int n_in,
                              void* d_out, int out_size, void* d_ws, size_t ws_size,
                              hipStream_t stream) {
    const float* in_features  = (const float*)d_in[0];
    const float* out_features = (const float*)d_in[1];
    const float* in_weights   = (const float*)d_in[2];
    const float* W1           = (const float*)d_in[3];
    const float* b1           = (const float*)d_in[4];
    const float* W2           = (const float*)d_in[5];
    const float* b2           = (const float*)d_in[6];
    const int*   nbr          = (const int*)d_in[7];
    const int*   rowptr       = (const int*)d_in[8];

    int N = in_sizes[2];           // in_weights has N elements
    int M = in_sizes[8] - 1;       // rowptr has M+1

    // Workspace: U (N x 64 bf16), S (M x 64 bf16)
    unsigned short* U = (unsigned short*)d_ws;
    unsigned short* S = U + (size_t)N * HDIM;

    int rows = N + M;
    int proj_blocks = (rows + 3) / 4;          // 4 waves per 256-thread block
    proj_kernel<<<proj_blocks, 256, 0, stream>>>(in_features, out_features, W1, b1,
                                                 U, S, N, M);

    int conv_blocks = (M + 3) / 4;
    conv_kernel<<<conv_blocks, 256, 0, stream>>>(U, S, nbr, rowptr, in_weights,
                                                 W2, b2, (float*)d_out, M);
}

// Round 4
// 147.278 us; speedup vs baseline: 1.5146x; 1.5146x over previous
//
#include <hip/hip_runtime.h>
#include <hip/hip_bf16.h>

#define C_IN 32
#define HDIM 64
#define C_OUT 32

__device__ __forceinline__ float bf16_to_f32(unsigned short u) {
    return __uint_as_float(((unsigned int)u) << 16);
}

__device__ __forceinline__ unsigned short f32_to_bf16(float f) {
    unsigned int x = __float_as_uint(f);
    x += 0x7fffu + ((x >> 16) & 1u);   // round-to-nearest-even
    return (unsigned short)(x >> 16);
}

__device__ __forceinline__ float readlane_f(float v, int t) {
    return __uint_as_float(__builtin_amdgcn_readlane(__float_as_uint(v), t));
}

// gelu, tanh form: 0.5x(1+tanh(0.79788456(x+0.044715x^3))) = x * sigmoid(2y)
// sigmoid(2y) = 1/(1+exp(-2y));  -2y = x*(-1.5957691 - 0.0713553*x^2)
// 5 VALU + 2 trans (vs 14+2 for the A&S erf). Max abs err vs exact gelu ~1e-3.
__device__ __forceinline__ float gelu_f(float x) {
    float x2 = x * x;
    float q  = fmaf(-0.0713553f, x2, -1.5957691f);   // always negative
    float e  = __expf(x * q);                        // exp(-2y); inf for very neg x -> rcp->0
    return x * __builtin_amdgcn_rcpf(1.0f + e);
}

// Phase 1+2: U[n] = in_features[n] @ W1[:32]          (bf16, N rows)
//            S[m] = out_features[m] @ W1[32:] + b1    (bf16, M rows)
// One wave per 16 rows. W1 column (32 floats) preloaded into VGPRs once per
// wave; x-row loaded by lanes 0..31 (one coalesced 128B load) and broadcast
// via v_readlane (VALU), so per-row cost is 1 VMEM + ~64 VALU instrs.
__global__ __launch_bounds__(256) void proj_kernel(
    const float* __restrict__ in_features, const float* __restrict__ out_features,
    const float* __restrict__ W1, const float* __restrict__ b1,
    unsigned short* __restrict__ U, unsigned short* __restrict__ S,
    int N, int M)
{
    const int ROWS = 16;
    int wid  = blockIdx.x * (blockDim.x >> 6) + (threadIdx.x >> 6);
    int lane = threadIdx.x & 63;
    int UW = (N + ROWS - 1) / ROWS;
    int SW = (M + ROWS - 1) / ROWS;
    if (wid >= UW + SW) return;
    bool isS = wid >= UW;
    int row0  = (isS ? wid - UW : wid) * ROWS;
    int nrows = min(ROWS, (isS ? M : N) - row0);
    const float* src = isS ? out_features : in_features;
    const float* w1  = W1 + (isS ? C_IN * HDIM : 0);
    unsigned short* dst = isS ? S : U;

    float w1c[C_IN];
#pragma unroll
    for (int k = 0; k < C_IN; ++k) w1c[k] = w1[k * HDIM + lane];
    float bias = isS ? b1[lane] : 0.0f;

    for (int r = 0; r < nrows; ++r) {
        size_t row = (size_t)(row0 + r);
        float xv = (lane < C_IN) ? src[row * C_IN + lane] : 0.0f;
        float acc0 = bias, acc1 = 0.0f;
#pragma unroll
        for (int k = 0; k < C_IN; k += 2) {
            acc0 = fmaf(readlane_f(xv, k),     w1c[k],     acc0);
            acc1 = fmaf(readlane_f(xv, k + 1), w1c[k + 1], acc1);
        }
        dst[row * HDIM + lane] = f32_to_bf16(acc0 + acc1);
    }
}

// Phase 3+4 fused: per segment m:
//   acc[lane] = sum_e w_e * gelu(U[idx_e][lane] + S[m][lane])
//   out[m][j] = (acc @ W2)[j]/cnt + b2[j]*wsum/cnt
// Neighbor id/weight broadcast via v_readlane (SGPR) -> SALU address math,
// SGPR operand in the fma. One wave per segment, 4 segments per block.
__global__ __launch_bounds__(256) void conv_kernel(
    const unsigned short* __restrict__ U, const unsigned short* __restrict__ S,
    const int* __restrict__ nbr, const int* __restrict__ rowptr,
    const float* __restrict__ in_weights,
    const float* __restrict__ W2, const float* __restrict__ b2,
    float* __restrict__ out, int M)
{
    __shared__ float lds_W2[HDIM * C_OUT];   // 8 KB
    __shared__ float lds_acc[4 * HDIM];      // 1 KB

    int tid = threadIdx.x;
#pragma unroll
    for (int i = tid; i < HDIM * C_OUT; i += 256) lds_W2[i] = W2[i];

    int wave = tid >> 6, lane = tid & 63;
    int m = blockIdx.x * 4 + wave;

    float acc = 0.0f, wsum = 0.0f;
    int cnt = 0;
    if (m < M) {
        int base = rowptr[m];
        cnt = rowptr[m + 1] - base;
        float s = bf16_to_f32(S[(size_t)m * HDIM + lane]);

        if (cnt == 32) {                       // DEG==32 fast path (always, here)
            int id = 0; float w = 0.0f;
            if (lane < 32) { int e = nbr[base + lane]; id = e; w = in_weights[e]; }
#pragma unroll
            for (int t = 0; t < 32; ++t) {
                unsigned sid = (unsigned)__builtin_amdgcn_readlane(id, t);
                float    wt  = readlane_f(w, t);
                float u = bf16_to_f32(U[(size_t)sid * HDIM + lane]);
                acc = fmaf(wt, gelu_f(u + s), acc);
            }
            wsum = w;                          // per-lane; reduced below
        } else {                               // generic fallback
            for (int t0 = 0; t0 < cnt; t0 += 64) {
                int chunk = min(64, cnt - t0);
                int id = 0; float w = 0.0f;
                if (lane < chunk) { int e = nbr[base + t0 + lane]; id = e; w = in_weights[e]; }
                for (int t = 0; t < chunk; ++t) {
                    unsigned sid = (unsigned)__builtin_amdgcn_readlane(id, t);
                    float    wt  = readlane_f(w, t);
                    float u = bf16_to_f32(U[(size_t)sid * HDIM + lane]);
                    acc = fmaf(wt, gelu_f(u + s), acc);
                }
                wsum += w;
            }
        }
#pragma unroll
        for (int off = 32; off >= 1; off >>= 1) wsum += __shfl_xor(wsum, off);
    }

    lds_acc[wave * HDIM + lane] = acc;
    __syncthreads();

    if (m < M) {
        int j = lane & 31, half = lane >> 5;
        float o = 0.0f;
#pragma unroll
        for (int k2 = 0; k2 < 32; ++k2) {
            int k = half * 32 + k2;
            o = fmaf(lds_acc[wave * HDIM + k], lds_W2[k * C_OUT + j], o);
        }
        o += __shfl_xor(o, 32);                // combine the two k-halves
        if (lane < 32) {
            float invc = 1.0f / (float)max(cnt, 1);
            out[(size_t)m * C_OUT + lane] = (o + b2[lane] * wsum) * invc;
        }
    }
}

extern "C" void kernel_launch(void* const* d_in, const int* in_sizes, int n_in,
                              void* d_out, int out_size, void* d_ws, size_t ws_size,
                              hipStream_t stream) {
    const float* in_features  = (const float*)d_in[0];
    const float* out_features = (const float*)d_in[1];
    const float* in_weights   = (const float*)d_in[2];
    const float* W1           = (const float*)d_in[3];
    const float* b1           = (const float*)d_in[4];
    const float* W2           = (const float*)d_in[5];
    const float* b2           = (const float*)d_in[6];
    const int*   nbr          = (const int*)d_in[7];
    const int*   rowptr       = (const int*)d_in[8];

    int N = in_sizes[2];           // in_weights has N elements
    int M = in_sizes[8] - 1;       // rowptr has M+1

    unsigned short* U = (unsigned short*)d_ws;              // N x 64 bf16
    unsigned short* S = U + (size_t)N * HDIM;               // M x 64 bf16

    const int ROWS = 16;
    int UW = (N + ROWS - 1) / ROWS;
    int SW = (M + ROWS - 1) / ROWS;
    int proj_blocks = (UW + SW + 3) / 4;       // 4 waves per block
    proj_kernel<<<proj_blocks, 256, 0, stream>>>(in_features, out_features, W1, b1,
                                                 U, S, N, M);

    int conv_blocks = (M + 3) / 4;
    conv_kernel<<<conv_blocks, 256, 0, stream>>>(U, S, nbr, rowptr, in_weights,
                                                 W2, b2, (float*)d_out, M);
}

// Round 5
// 142.315 us; speedup vs baseline: 1.5674x; 1.0349x over previous
//
#include <hip/hip_runtime.h>
#include <hip/hip_bf16.h>

#define C_IN 32
#define HDIM 64
#define C_OUT 32

__device__ __forceinline__ float bf16_to_f32(unsigned short u) {
    return __uint_as_float(((unsigned int)u) << 16);
}

__device__ __forceinline__ unsigned short f32_to_bf16(float f) {
    unsigned int x = __float_as_uint(f);
    x += 0x7fffu + ((x >> 16) & 1u);   // round-to-nearest-even
    return (unsigned short)(x >> 16);
}

__device__ __forceinline__ float readlane_f(float v, int t) {
    return __uint_as_float(__builtin_amdgcn_readlane(__float_as_uint(v), t));
}

// gelu, tanh form: x * sigmoid(1.5957691x + 0.0713553x^3). ~1e-3 max abs err.
__device__ __forceinline__ float gelu_f(float x) {
    float x2 = x * x;
    float e  = __expf(x * fmaf(-0.0713553f, x2, -1.5957691f));
    return x * __builtin_amdgcn_rcpf(1.0f + e);
}

// Phase 1+2: U[n] = in_features[n] @ W1[:32]          (bf16, N rows)
//            S[m] = out_features[m] @ W1[32:] + b1    (bf16, M rows)
// One wave per 16 rows. W1 column (32 floats) in VGPRs once per wave.
// Row base address is wave-uniform (readfirstlane) -> the x-row reads become
// s_load_dwordx16 into SGPRs; the 32 MACs are v_fma with SGPR operand.
__global__ __launch_bounds__(256) void proj_kernel(
    const float* __restrict__ in_features, const float* __restrict__ out_features,
    const float* __restrict__ W1, const float* __restrict__ b1,
    unsigned short* __restrict__ U, unsigned short* __restrict__ S,
    int N, int M)
{
    const int ROWS = 16;
    int lane = threadIdx.x & 63;
    int wid  = __builtin_amdgcn_readfirstlane(
                   blockIdx.x * (blockDim.x >> 6) + (threadIdx.x >> 6));
    int UW = (N + ROWS - 1) / ROWS;
    int SW = (M + ROWS - 1) / ROWS;
    if (wid >= UW + SW) return;
    bool isS = wid >= UW;
    int row0  = (isS ? wid - UW : wid) * ROWS;
    int nrows = min(ROWS, (isS ? M : N) - row0);
    const float* __restrict__ src = isS ? out_features : in_features;
    const float* __restrict__ w1  = W1 + (isS ? C_IN * HDIM : 0);
    unsigned short* __restrict__ dst = isS ? S : U;

    float w1c[C_IN];
#pragma unroll
    for (int k = 0; k < C_IN; ++k) w1c[k] = w1[k * HDIM + lane];
    float bias = isS ? b1[lane] : 0.0f;

    for (int r = 0; r < nrows; ++r) {
        size_t row = (size_t)(row0 + r);
        const float* __restrict__ xr = src + row * C_IN;   // wave-uniform
        float acc0 = bias, acc1 = 0.0f;
#pragma unroll
        for (int k = 0; k < C_IN; k += 2) {
            acc0 = fmaf(xr[k],     w1c[k],     acc0);      // s_load + v_fma(sgpr)
            acc1 = fmaf(xr[k + 1], w1c[k + 1], acc1);
        }
        dst[row * HDIM + lane] = f32_to_bf16(acc0 + acc1);
    }
}

// Phase 3+4 fused, per segment m (one wave, lane = hidden channel):
//   acc[lane] = sum_e w_e * gelu(U[idx_e][lane] + S[m][lane])
//   out[m][j] = (acc @ W2)[j]/cnt + b2[j]*wsum/cnt
// DEG==32 fast path: 8-deep explicit prefetch ring (q0..q7, static names,
// fully unrolled) so U-row gathers for edge t+8 are in flight while edge t
// computes -- hides the ~200-400cy L2/LLC gather latency the compiler's
// 16-VGPR serial schedule exposed.
__global__ __launch_bounds__(256) void conv_kernel(
    const unsigned short* __restrict__ U, const unsigned short* __restrict__ S,
    const int* __restrict__ nbr, const int* __restrict__ rowptr,
    const float* __restrict__ in_weights,
    const float* __restrict__ W2, const float* __restrict__ b2,
    float* __restrict__ out, int M)
{
    __shared__ float lds_W2[HDIM * C_OUT];   // 8 KB
    __shared__ float lds_acc[4 * HDIM];      // 1 KB

    int tid = threadIdx.x;
#pragma unroll
    for (int i = tid; i < HDIM * C_OUT; i += 256) lds_W2[i] = W2[i];

    int wave = tid >> 6, lane = tid & 63;
    int m = blockIdx.x * 4 + wave;

    float acc = 0.0f, wsum = 0.0f;
    int cnt = 0;
    if (m < M) {
        int base = rowptr[m];
        cnt = rowptr[m + 1] - base;
        float s = bf16_to_f32(S[(size_t)m * HDIM + lane]);

        if (cnt == 32) {                       // DEG==32 fast path
            int id = 0; float w = 0.0f;
            if (lane < 32) { int e = nbr[base + lane]; id = e; w = in_weights[e]; }
            wsum = w;                          // per-lane; reduced below

#define UADDR(t) (U + ((size_t)(unsigned)__builtin_amdgcn_readlane(id, (t))) * HDIM + lane)
            unsigned short q0, q1, q2, q3, q4, q5, q6, q7;
            q0 = *UADDR(0); q1 = *UADDR(1); q2 = *UADDR(2); q3 = *UADDR(3);
            q4 = *UADDR(4); q5 = *UADDR(5); q6 = *UADDR(6); q7 = *UADDR(7);

#define PSTEP(t, qr, nt) { \
            float wt = readlane_f(w, (t)); \
            float x  = __uint_as_float(((unsigned)(qr)) << 16) + s; \
            acc = fmaf(wt, gelu_f(x), acc); \
            if ((nt) < 32) qr = *UADDR(nt); }

            PSTEP(0,  q0, 8)  PSTEP(1,  q1, 9)  PSTEP(2,  q2, 10) PSTEP(3,  q3, 11)
            PSTEP(4,  q4, 12) PSTEP(5,  q5, 13) PSTEP(6,  q6, 14) PSTEP(7,  q7, 15)
            PSTEP(8,  q0, 16) PSTEP(9,  q1, 17) PSTEP(10, q2, 18) PSTEP(11, q3, 19)
            PSTEP(12, q4, 20) PSTEP(13, q5, 21) PSTEP(14, q6, 22) PSTEP(15, q7, 23)
            PSTEP(16, q0, 24) PSTEP(17, q1, 25) PSTEP(18, q2, 26) PSTEP(19, q3, 27)
            PSTEP(20, q4, 28) PSTEP(21, q5, 29) PSTEP(22, q6, 30) PSTEP(23, q7, 31)
            PSTEP(24, q0, 32) PSTEP(25, q1, 33) PSTEP(26, q2, 34) PSTEP(27, q3, 35)
            PSTEP(28, q4, 36) PSTEP(29, q5, 37) PSTEP(30, q6, 38) PSTEP(31, q7, 39)
#undef PSTEP
#undef UADDR
        } else {                               // generic fallback
            for (int t0 = 0; t0 < cnt; t0 += 64) {
                int chunk = min(64, cnt - t0);
                int id = 0; float w = 0.0f;
                if (lane < chunk) { int e = nbr[base + t0 + lane]; id = e; w = in_weights[e]; }
                for (int t = 0; t < chunk; ++t) {
                    unsigned sid = (unsigned)__builtin_amdgcn_readlane(id, t);
                    float    wt  = readlane_f(w, t);
                    float u = bf16_to_f32(U[(size_t)sid * HDIM + lane]);
                    acc = fmaf(wt, gelu_f(u + s), acc);
                }
                wsum += w;
            }
        }
#pragma unroll
        for (int off = 32; off >= 1; off >>= 1) wsum += __shfl_xor(wsum, off);
    }

    lds_acc[wave * HDIM + lane] = acc;
    __syncthreads();

    if (m < M) {
        int j = lane & 31, half = lane >> 5;
        float o = 0.0f;
#pragma unroll
        for (int k2 = 0; k2 < 32; ++k2) {
            int k = half * 32 + k2;
            o = fmaf(lds_acc[wave * HDIM + k], lds_W2[k * C_OUT + j], o);
        }
        o += __shfl_xor(o, 32);                // combine the two k-halves
        if (lane < 32) {
            float invc = 1.0f / (float)max(cnt, 1);
            out[(size_t)m * C_OUT + lane] = (o + b2[lane] * wsum) * invc;
        }
    }
}

extern "C" void kernel_launch(void* const* d_in, const int* in_sizes, int n_in,
                              void* d_out, int out_size, void* d_ws, size_t ws_size,
                              hipStream_t stream) {
    const float* in_features  = (const float*)d_in[0];
    const float* out_features = (const float*)d_in[1];
    const float* in_weights   = (const float*)d_in[2];
    const float* W1           = (const float*)d_in[3];
    const float* b1           = (const float*)d_in[4];
    const float* W2           = (const float*)d_in[5];
    const float* b2           = (const float*)d_in[6];
    const int*   nbr          = (const int*)d_in[7];
    const int*   rowptr       = (const int*)d_in[8];

    int N = in_sizes[2];           // in_weights has N elements
    int M = in_sizes[8] - 1;       // rowptr has M+1

    unsigned short* U = (unsigned short*)d_ws;              // N x 64 bf16
    unsigned short* S = U + (size_t)N * HDIM;               // M x 64 bf16

    const int ROWS = 16;
    int UW = (N + ROWS - 1) / ROWS;
    int SW = (M + ROWS - 1) / ROWS;
    int proj_blocks = (UW + SW + 3) / 4;       // 4 waves per block
    proj_kernel<<<proj_blocks, 256, 0, stream>>>(in_features, out_features, W1, b1,
                                                 U, S, N, M);

    int conv_blocks = (M + 3) / 4;
    conv_kernel<<<conv_blocks, 256, 0, stream>>>(U, S, nbr, rowptr, in_weights,
                                                 W2, b2, (float*)d_out, M);
}